// Round 7
// baseline (88.392 us; speedup 1.0000x reference)
//
#include <hip/hip_runtime.h>
#include <math.h>

#define DIM    2048
#define NEXP   64
#define BM     128
#define BK     32
#define TPB    128
#define XPAD   132   // x tile row stride (floats), mult-of-4, ≡4 mod 32
#define WPAD   68    // w tile row stride (floats), mult-of-4, ≡4 mod 32

typedef float f32x2 __attribute__((ext_vector_type(2)));
typedef float f32x4 __attribute__((ext_vector_type(4)));

// XOR swizzle (units of 4 floats). Row stride ≡4 mod 32 => transposed staging
// writes land 2 lanes/bank (free), compute reads stay broadcast + 2-way.
#define SW(k) ((((k) >> 1) & 7) << 2)

// ---------------- Kernel 1: partial logits GEMM (packed fp32 FMA) ------------
// Tile: 128 tokens x 64 experts, 128 threads, per-thread 8 tok x 8 exp.
// LDS transposed [K][M], XOR-swizzled; register prefetch of next chunk.
__global__ __launch_bounds__(TPB)
void router_part(const float* __restrict__ x, const float* __restrict__ Wg,
                 float* __restrict__ part, int n_tokens, int ks) {
    __shared__ float xT[BK][XPAD];   // 16.9 KB
    __shared__ float wT[BK][WPAD];   //  8.7 KB

    const int tid   = threadIdx.x;
    const int nblkt = n_tokens / BM;            // 128
    const int tb    = blockIdx.x % nblkt;
    const int s     = blockIdx.x / nblkt;       // K-split index
    const int KC    = DIM / ks;
    const int k0    = s * KC;
    const int t0    = tb * BM;

    // compute map: 8 tok x 8 exp per thread
    const int tt = tid >> 3;                    // 0..15 token octet
    const int ee = tid & 7;                     // 0..7  expert octet
    // staging map
    const int wrow  = tid & 63;                 // W row 0..63
    const int whalf = tid >> 6;                 // 0/1: which 16-k half

    f32x2 acc[8][4];                            // [token i][expert pair]
#pragma unroll
    for (int i = 0; i < 8; ++i)
#pragma unroll
        for (int jp = 0; jp < 4; ++jp) acc[i][jp] = (f32x2)(0.f);

    f32x4 px[8], pw[4];
    const float* xrow = x + (size_t)(t0 + tid) * DIM + k0;      // own row
    const float* wrp  = Wg + (size_t)wrow * DIM + k0 + whalf * 16;
    {   // prologue: load chunk 0 (1 HBM line per lane for x)
#pragma unroll
        for (int q = 0; q < 8; ++q) px[q] = *(const f32x4*)(xrow + q * 4);
#pragma unroll
        for (int q = 0; q < 4; ++q) pw[q] = *(const f32x4*)(wrp + q * 4);
    }

    const int nch = KC / BK;
    for (int c = 0; c < nch; ++c) {
        __syncthreads();   // previous chunk's compute done -> LDS reusable
        // transposed+swizzled scatter (every write 2 lanes/bank = free)
#pragma unroll
        for (int q = 0; q < 8; ++q)
#pragma unroll
            for (int j = 0; j < 4; ++j) {
                const int k = q * 4 + j;
                xT[k][tid ^ SW(k)] = px[q][j];
            }
#pragma unroll
        for (int q = 0; q < 4; ++q)
#pragma unroll
            for (int j = 0; j < 4; ++j) {
                const int k = whalf * 16 + q * 4 + j;
                wT[k][wrow ^ SW(k)] = pw[q][j];
            }
        // issue next chunk's global loads (in flight across compute)
        if (c + 1 < nch) {
            const float* xn = xrow + (c + 1) * BK;
#pragma unroll
            for (int q = 0; q < 8; ++q) px[q] = *(const f32x4*)(xn + q * 4);
            const float* wn = wrp + (c + 1) * BK;
#pragma unroll
            for (int q = 0; q < 4; ++q) pw[q] = *(const f32x4*)(wn + q * 4);
        }
        __syncthreads();   // staging visible
        // compute: per kk, 4 conflict-free b128 reads + 32 v_pk_fma_f32
#pragma unroll
        for (int kk = 0; kk < BK; ++kk) {
            const int sw = SW(kk);
            f32x4 xv0 = *(const f32x4*)&xT[kk][(tt * 8) ^ sw];
            f32x4 xv1 = *(const f32x4*)&xT[kk][(tt * 8 + 4) ^ sw];
            f32x4 w0  = *(const f32x4*)&wT[kk][(ee * 8) ^ sw];
            f32x4 w1  = *(const f32x4*)&wT[kk][(ee * 8 + 4) ^ sw];
            f32x2 wp0 = {w0.x, w0.y}, wp1 = {w0.z, w0.w};
            f32x2 wp2 = {w1.x, w1.y}, wp3 = {w1.z, w1.w};
#pragma unroll
            for (int i = 0; i < 4; ++i) {
                f32x2 xa = {xv0[i], xv0[i]};
                acc[i][0] = __builtin_elementwise_fma(xa, wp0, acc[i][0]);
                acc[i][1] = __builtin_elementwise_fma(xa, wp1, acc[i][1]);
                acc[i][2] = __builtin_elementwise_fma(xa, wp2, acc[i][2]);
                acc[i][3] = __builtin_elementwise_fma(xa, wp3, acc[i][3]);
                f32x2 xb = {xv1[i], xv1[i]};
                acc[4 + i][0] = __builtin_elementwise_fma(xb, wp0, acc[4 + i][0]);
                acc[4 + i][1] = __builtin_elementwise_fma(xb, wp1, acc[4 + i][1]);
                acc[4 + i][2] = __builtin_elementwise_fma(xb, wp2, acc[4 + i][2]);
                acc[4 + i][3] = __builtin_elementwise_fma(xb, wp3, acc[4 + i][3]);
            }
        }
    }

    // store partials: part[(tok*ks + s)*64 + e], 2 x f32x4 per token
#pragma unroll
    for (int i = 0; i < 8; ++i) {
        const int t = t0 + tt * 8 + i;
        float* pb = part + ((size_t)t * ks + s) * NEXP + ee * 8;
        f32x4 v0, v1;
        v0.x = acc[i][0].x; v0.y = acc[i][0].y; v0.z = acc[i][1].x; v0.w = acc[i][1].y;
        v1.x = acc[i][2].x; v1.y = acc[i][2].y; v1.z = acc[i][3].x; v1.w = acc[i][3].y;
        *(f32x4*)(pb)     = v0;
        *(f32x4*)(pb + 4) = v1;
    }
}

// ---------------- Kernel 2: reduce partials + softmax + top-2 + aux ----------
#define FTPB 64
__global__ __launch_bounds__(FTPB)
void router_finish(const float* __restrict__ part, float* __restrict__ out,
                   float* __restrict__ gCnt, float* __restrict__ gPsum,
                   int n_tokens, int ks) {
    __shared__ float pl[FTPB][NEXP + 1];
    __shared__ float cnt[NEXP];
    const int tid = threadIdx.x;
    const int tok = blockIdx.x * FTPB + tid;
    cnt[tid] = 0.f;                            // FTPB == NEXP
    __syncthreads();

    const float* pb = part + (size_t)tok * ks * NEXP;
    float lg[NEXP];
#pragma unroll
    for (int q = 0; q < 16; ++q) {
        f32x4 a = *(const f32x4*)(pb + q * 4);
        lg[q * 4 + 0] = a.x; lg[q * 4 + 1] = a.y;
        lg[q * 4 + 2] = a.z; lg[q * 4 + 3] = a.w;
    }
    for (int s2 = 1; s2 < ks; ++s2) {
#pragma unroll
        for (int q = 0; q < 16; ++q) {
            f32x4 a = *(const f32x4*)(pb + (size_t)s2 * NEXP + q * 4);
            lg[q * 4 + 0] += a.x; lg[q * 4 + 1] += a.y;
            lg[q * 4 + 2] += a.z; lg[q * 4 + 3] += a.w;
        }
    }

    // top-2 (strict > keeps lowest index on ties, matching lax.top_k)
    float m1 = -1e30f, m2 = -1e30f;
    int i1 = 0, i2 = 0;
#pragma unroll
    for (int e = 0; e < NEXP; ++e) {
        float l = lg[e];
        if (l > m1)      { m2 = m1; i2 = i1; m1 = l; i1 = e; }
        else if (l > m2) { m2 = l; i2 = e; }
    }

    float ssum = 0.f;
#pragma unroll
    for (int e = 0; e < NEXP; ++e) {
        float p = __expf(lg[e] - m1);
        lg[e] = p;
        ssum += p;
    }
    const float inv_s = 1.f / ssum;
#pragma unroll
    for (int e = 0; e < NEXP; ++e) pl[tid][e] = lg[e] * inv_s;

    const float p1 = inv_s;                    // exp(0)*inv_s
    const float p2 = __expf(m2 - m1) * inv_s;
    const float d  = p1 + p2 + 1e-8f;
    out[(size_t)tok * 2]     = (float)i1;
    out[(size_t)tok * 2 + 1] = (float)i2;
    out[(size_t)n_tokens * 2 + (size_t)tok * 2]     = p1 / d;
    out[(size_t)n_tokens * 2 + (size_t)tok * 2 + 1] = p2 / d;
    atomicAdd(&cnt[i1], 1.f);
    atomicAdd(&cnt[i2], 1.f);
    __syncthreads();

    // per-expert column sums of router_probs (thread e handles expert e)
    {
        float cs = 0.f;
#pragma unroll 8
        for (int t = 0; t < FTPB; ++t) cs += pl[t][tid];
        atomicAdd(&gPsum[tid], cs);
        atomicAdd(&gCnt[tid], cnt[tid]);
    }
}

// ---------------- Kernel 3: final aux loss -----------------------------------
__global__ void router_aux(const float* __restrict__ gCnt,
                           const float* __restrict__ gPsum,
                           float* __restrict__ out, int n_tokens) {
    const int e = threadIdx.x;
    float f = gCnt[e] / (float)(n_tokens * 2);
    float P = gPsum[e] / (float)n_tokens;
    float v = f * P;
#pragma unroll
    for (int o = 32; o > 0; o >>= 1) v += __shfl_down(v, o);
    if (e == 0) out[(size_t)n_tokens * 4] = 64.f * v;
}

extern "C" void kernel_launch(void* const* d_in, const int* in_sizes, int n_in,
                              void* d_out, int out_size, void* d_ws, size_t ws_size,
                              hipStream_t stream) {
    const float* x  = (const float*)d_in[0];
    const float* Wg = (const float*)d_in[1];
    float* out = (float*)d_out;
    const int n_tokens = in_sizes[0] / DIM;   // 16384

    // largest K-split whose partial buffer fits the workspace
    int ks = 8;
    while (ks > 1 &&
           (2 * NEXP + (size_t)ks * n_tokens * NEXP) * sizeof(float) > ws_size)
        ks >>= 1;

    float* gCnt  = (float*)d_ws;
    float* gPsum = gCnt + NEXP;
    float* partb = gPsum + NEXP;

    hipMemsetAsync(d_ws, 0, 2 * NEXP * sizeof(float), stream);
    hipLaunchKernelGGL(router_part, dim3((n_tokens / BM) * ks), dim3(TPB), 0, stream,
                       x, Wg, partb, n_tokens, ks);
    hipLaunchKernelGGL(router_finish, dim3(n_tokens / FTPB), dim3(FTPB), 0, stream,
                       partb, out, gCnt, gPsum, n_tokens, ks);
    hipLaunchKernelGGL(router_aux, dim3(1), dim3(NEXP), 0, stream,
                       gCnt, gPsum, out, n_tokens);
}